// Round 6
// baseline (343.891 us; speedup 1.0000x reference)
//
#include <hip/hip_runtime.h>

#define H 1024
#define UNITS 1024
#define BATCH 32
#define SEQ 2048
#define M_TOT (BATCH * SEQ)  // 65536

typedef __attribute__((ext_vector_type(8))) short bf16x8;
typedef __attribute__((ext_vector_type(8))) unsigned short u16x8;
typedef __attribute__((ext_vector_type(4))) float f32x4;

__device__ __forceinline__ unsigned short f2bf(float f) {
  union { float f; unsigned u; } x; x.f = f;
  unsigned r = x.u + 0x7FFFu + ((x.u >> 16) & 1u);  // RTN-even
  return (unsigned short)(r >> 16);
}
__device__ __forceinline__ float bf2f(unsigned short h) {
  union { unsigned u; float f; } x; x.u = (unsigned)h << 16;
  return x.f;
}

// async global->LDS, 16B per lane; LDS dest = wave-uniform base + lane*16
__device__ __forceinline__ void gll16(const unsigned short* g, unsigned short* l) {
  __builtin_amdgcn_global_load_lds(
      (const __attribute__((address_space(1))) void*)g,
      (__attribute__((address_space(3))) void*)l, 16, 0, 0);
}

// ---- values fp32 -> bf16 (one-shot, BW-bound) ----
__global__ void k_cast(const float* __restrict__ in, unsigned short* __restrict__ out) {
  size_t i = ((size_t)blockIdx.x * 256 + threadIdx.x) * 8;
  float4 v0 = *reinterpret_cast<const float4*>(in + i);
  float4 v1 = *reinterpret_cast<const float4*>(in + i + 4);
  union { unsigned short h[8]; u16x8 v; } p;
  p.h[0] = f2bf(v0.x); p.h[1] = f2bf(v0.y); p.h[2] = f2bf(v0.z); p.h[3] = f2bf(v0.w);
  p.h[4] = f2bf(v1.x); p.h[5] = f2bf(v1.y); p.h[6] = f2bf(v1.z); p.h[7] = f2bf(v1.w);
  *reinterpret_cast<u16x8*>(out + i) = p.v;
}

// ---- W1 [H][U] fp32 -> W1T [U][H] bf16 ----
__global__ void k_transpose_w1(const float* __restrict__ W1, unsigned short* __restrict__ W1T) {
  __shared__ float tile[32][33];
  int bx = blockIdx.x, by = blockIdx.y;
  int tx = threadIdx.x, ty = threadIdx.y;
#pragma unroll
  for (int i = 0; i < 4; ++i)
    tile[ty + i * 8][tx] = W1[(by * 32 + ty + i * 8) * UNITS + bx * 32 + tx];
  __syncthreads();
#pragma unroll
  for (int i = 0; i < 4; ++i)
    W1T[(bx * 32 + ty + i * 8) * H + by * 32 + tx] = f2bf(tile[tx][ty + i * 8]);
}

// ---- projq[b][u] = query[b,:] @ W2[:,u] + b2[u]  (fp32) ----
__global__ void k_projq(const float* __restrict__ query, const float* __restrict__ W2,
                        const float* __restrict__ b2, float* __restrict__ projq) {
  __shared__ float q[H];
  int b = blockIdx.x;
  int u = blockIdx.y * 256 + threadIdx.x;
  for (int i = threadIdx.x; i < H; i += 256) q[i] = query[b * H + i];
  __syncthreads();
  float acc = 0.f;
#pragma unroll 8
  for (int k = 0; k < H; ++k) acc = fmaf(q[k], W2[k * UNITS + u], acc);
  projq[b * UNITS + u] = acc + b2[u];
}

// ============ 256x256 8-phase fused GEMM + tanh + dot(V) -> scores ===========
// T3+T4+T5 template + slot swizzle. LDS [2 dbuf][2 khalf][256 rows][32 halves];
// rows are 64 B = 4 x 16 B slots. Row stride (16 banks) aliases rows 2 apart,
// so un-swizzled frag reads are 8-way bank conflicts (R4: 1.26e7, MfmaUtil 29%).
// Swizzle: physical slot = logical slot ^ ((row>>2)&3) -- period 16 rows
// matches the frag-read group, giving exactly 2 lanes/bank-quad per
// quarter-wave (the wave64 floor; 2-way is free, m136). Store side keeps LDS
// linear (gll16 requirement) and pre-swizzles the GLOBAL source column with
// the same involution (rule 21): scol = ((lane&3) ^ ((lane>>4)&3)) << 3.
// Counted vmcnt(4) only at phases 0/2; never drained to 0 in the loop.
#define BM 256
#define BN 256
#define NT 16  // K-tiles of 64

__global__ __launch_bounds__(512, 2) void k_score3(
    const unsigned short* __restrict__ Vb,   // values bf16 [M_TOT][H]
    const unsigned short* __restrict__ W1T,  // [UNITS][H] bf16
    const float* __restrict__ b1,
    const float* __restrict__ projq,         // [BATCH][UNITS]
    const float* __restrict__ V,
    float* __restrict__ scores)              // [M_TOT], pre-zeroed
{
  __shared__ unsigned short As[2][2][256][32];  // 64 KB
  __shared__ unsigned short Bs[2][2][256][32];  // 64 KB

  const int tid = threadIdx.x;
  const int lane = tid & 63;
  const int wave = tid >> 6;        // 0..7
  const int wm = wave >> 2;         // 0..1 -> rows wm*128..+128
  const int wn = wave & 3;          // 0..3 -> cols wn*64..+64
  const int li = lane & 15, hi = lane >> 4;
  const int csw = ((hi ^ (li >> 2)) & 3) << 3;  // swizzled slot col (halves)

  // XCD-bijective swizzle: all 4 N-tiles of an M-tile on one XCD, consecutive.
  const int g = blockIdx.x;
  const int xcd = g & 7;
  const int local = g >> 3;          // 0..127
  const int n_t = local & 3;
  const int m_t = xcd + ((local >> 2) << 3);  // 0..255, bijective
  const int m0 = m_t * BM;
  const int n0 = n_t * BN;

  // staging geometry: chunk = 16 rows x 64 B; 2 chunks per wave per half-stage
  const int srow = wave * 32 + (lane >> 2);                   // row offset in tile
  const int scol = (((lane & 3) ^ ((lane >> 4) & 3)) << 3);   // pre-swizzled source col

  auto STAGE_A = [&](int bf, int kt, int kh) {
    const unsigned short* src =
        Vb + (size_t)(m0 + srow) * H + kt * 64 + kh * 32 + scol;
    unsigned short* dst = &As[bf][kh][wave * 32][0];
    gll16(src, dst);
    gll16(src + (size_t)16 * H, dst + 16 * 32);
  };
  auto STAGE_B = [&](int bf, int kt, int kh) {
    const unsigned short* src =
        W1T + (size_t)(n0 + srow) * H + kt * 64 + kh * 32 + scol;
    unsigned short* dst = &Bs[bf][kh][wave * 32][0];
    gll16(src, dst);
    gll16(src + (size_t)16 * H, dst + 16 * 32);
  };

  f32x4 acc[8][4] = {};

  // prologue: K-tile 0 -> buf 0, issue order A0,B0,A1,B1 (ledger depends on it)
  STAGE_A(0, 0, 0);
  STAGE_B(0, 0, 0);
  STAGE_A(0, 0, 1);
  STAGE_B(0, 0, 1);

#pragma unroll 2
  for (int c = 0; c < NT; ++c) {
    const int buf = c & 1, nbuf = buf ^ 1;
    const int cn = (c < NT - 1) ? c + 1 : NT - 1;  // tail: dummy re-stage

    bf16x8 a[8], b0, b1v;

    // ---- phase 0: kh=0, nh=0 ----
    asm volatile("s_waitcnt vmcnt(4)" ::: "memory");  // A0(c),B0(c) landed
    __builtin_amdgcn_s_barrier();
    STAGE_A(nbuf, cn, 0);
#pragma unroll
    for (int i = 0; i < 8; ++i)
      a[i] = *reinterpret_cast<const bf16x8*>(&As[buf][0][wm * 128 + i * 16 + li][csw]);
    b0  = *reinterpret_cast<const bf16x8*>(&Bs[buf][0][wn * 64 + 0 * 16 + li][csw]);
    b1v = *reinterpret_cast<const bf16x8*>(&Bs[buf][0][wn * 64 + 1 * 16 + li][csw]);
    __builtin_amdgcn_s_setprio(1);
#pragma unroll
    for (int i = 0; i < 8; ++i) {
      acc[i][0] = __builtin_amdgcn_mfma_f32_16x16x32_bf16(a[i], b0, acc[i][0], 0, 0, 0);
      acc[i][1] = __builtin_amdgcn_mfma_f32_16x16x32_bf16(a[i], b1v, acc[i][1], 0, 0, 0);
    }
    __builtin_amdgcn_s_setprio(0);

    // ---- phase 1: kh=0, nh=1 ----
    STAGE_B(nbuf, cn, 0);
    b0  = *reinterpret_cast<const bf16x8*>(&Bs[buf][0][wn * 64 + 2 * 16 + li][csw]);
    b1v = *reinterpret_cast<const bf16x8*>(&Bs[buf][0][wn * 64 + 3 * 16 + li][csw]);
    __builtin_amdgcn_s_setprio(1);
#pragma unroll
    for (int i = 0; i < 8; ++i) {
      acc[i][2] = __builtin_amdgcn_mfma_f32_16x16x32_bf16(a[i], b0, acc[i][2], 0, 0, 0);
      acc[i][3] = __builtin_amdgcn_mfma_f32_16x16x32_bf16(a[i], b1v, acc[i][3], 0, 0, 0);
    }
    __builtin_amdgcn_s_setprio(0);

    // ---- phase 2: kh=1, nh=0 ----
    asm volatile("s_waitcnt vmcnt(4)" ::: "memory");  // A1(c),B1(c) landed
    __builtin_amdgcn_s_barrier();
    STAGE_A(nbuf, cn, 1);
#pragma unroll
    for (int i = 0; i < 8; ++i)
      a[i] = *reinterpret_cast<const bf16x8*>(&As[buf][1][wm * 128 + i * 16 + li][csw]);
    b0  = *reinterpret_cast<const bf16x8*>(&Bs[buf][1][wn * 64 + 0 * 16 + li][csw]);
    b1v = *reinterpret_cast<const bf16x8*>(&Bs[buf][1][wn * 64 + 1 * 16 + li][csw]);
    __builtin_amdgcn_s_setprio(1);
#pragma unroll
    for (int i = 0; i < 8; ++i) {
      acc[i][0] = __builtin_amdgcn_mfma_f32_16x16x32_bf16(a[i], b0, acc[i][0], 0, 0, 0);
      acc[i][1] = __builtin_amdgcn_mfma_f32_16x16x32_bf16(a[i], b1v, acc[i][1], 0, 0, 0);
    }
    __builtin_amdgcn_s_setprio(0);

    // ---- phase 3: kh=1, nh=1 ----
    STAGE_B(nbuf, cn, 1);
    b0  = *reinterpret_cast<const bf16x8*>(&Bs[buf][1][wn * 64 + 2 * 16 + li][csw]);
    b1v = *reinterpret_cast<const bf16x8*>(&Bs[buf][1][wn * 64 + 3 * 16 + li][csw]);
    __builtin_amdgcn_s_setprio(1);
#pragma unroll
    for (int i = 0; i < 8; ++i) {
      acc[i][2] = __builtin_amdgcn_mfma_f32_16x16x32_bf16(a[i], b0, acc[i][2], 0, 0, 0);
      acc[i][3] = __builtin_amdgcn_mfma_f32_16x16x32_bf16(a[i], b1v, acc[i][3], 0, 0, 0);
    }
    __builtin_amdgcn_s_setprio(0);
  }

  // epilogue: partial score[row] = sum_u tanh(acc + b1[u] + projq[b][u]) * V[u]
  const int b = m0 >> 11;  // BM=256 divides SEQ=2048 -> batch uniform per block
  float bias[4], vv[4];
#pragma unroll
  for (int j = 0; j < 4; ++j) {
    int u = n0 + wn * 64 + j * 16 + li;
    bias[j] = b1[u] + projq[b * UNITS + u];
    vv[j] = V[u];
  }
#pragma unroll
  for (int mi = 0; mi < 8; ++mi) {
#pragma unroll
    for (int r = 0; r < 4; ++r) {
      float s = 0.f;
#pragma unroll
      for (int j = 0; j < 4; ++j) {
        float x = acc[mi][j][r] + bias[j];
        float e = __expf(2.f * x);       // tanh(x) = 1 - 2/(e^(2x)+1)
        s += (1.f - 2.f / (e + 1.f)) * vv[j];
      }
      s += __shfl_xor(s, 1);
      s += __shfl_xor(s, 2);
      s += __shfl_xor(s, 4);
      s += __shfl_xor(s, 8);
      if (li == 0) {
        int row = m0 + wm * 128 + mi * 16 + hi * 4 + r;
        atomicAdd(&scores[row], s);
      }
    }
  }
}

// ---- fallback fp32-A score kernel (used only if ws too small) ----
#define FBM 128
#define FBN 128
#define FBK 64
#define LDK 72
__global__ __launch_bounds__(256) void k_score_f32(
    const float* __restrict__ values, const unsigned short* __restrict__ W1T,
    const float* __restrict__ b1, const float* __restrict__ projq,
    const float* __restrict__ V, float* __restrict__ scores)
{
  __shared__ unsigned short Asf[FBM][LDK];
  __shared__ unsigned short Bsf[FBN][LDK];
  const int tid = threadIdx.x;
  const int lane = tid & 63;
  const int wave = tid >> 6;
  const int wm = wave >> 1, wn = wave & 1;
  const int li = lane & 15, hi = lane >> 4;
  const int n0 = blockIdx.x * FBN;
  const int m0 = blockIdx.y * FBM;
  f32x4 acc[4][4] = {};
  for (int k0 = 0; k0 < H; k0 += FBK) {
    __syncthreads();
#pragma unroll
    for (int q = 0; q < 8; ++q) {
      int idx = q * 256 + tid;
      int row = idx >> 4;
      int kc = (idx & 15) << 2;
      float4 v = *reinterpret_cast<const float4*>(&values[(size_t)(m0 + row) * H + k0 + kc]);
      union { unsigned short h[4]; unsigned long long u64; } p;
      p.h[0] = f2bf(v.x); p.h[1] = f2bf(v.y); p.h[2] = f2bf(v.z); p.h[3] = f2bf(v.w);
      *reinterpret_cast<unsigned long long*>(&Asf[row][kc]) = p.u64;
    }
#pragma unroll
    for (int q = 0; q < 4; ++q) {
      int idx = q * 256 + tid;
      int row = idx >> 3;
      int kc = (idx & 7) << 3;
      *reinterpret_cast<u16x8*>(&Bsf[row][kc]) =
          *reinterpret_cast<const u16x8*>(&W1T[(size_t)(n0 + row) * H + k0 + kc]);
    }
    __syncthreads();
#pragma unroll
    for (int ks = 0; ks < 2; ++ks) {
      const int kofs = ks * 32 + 8 * hi;
      bf16x8 a[4], bb[4];
#pragma unroll
      for (int i = 0; i < 4; ++i)
        a[i] = *reinterpret_cast<const bf16x8*>(&Asf[wm * 64 + i * 16 + li][kofs]);
#pragma unroll
      for (int i = 0; i < 4; ++i)
        bb[i] = *reinterpret_cast<const bf16x8*>(&Bsf[wn * 64 + i * 16 + li][kofs]);
#pragma unroll
      for (int mi = 0; mi < 4; ++mi)
#pragma unroll
        for (int ni = 0; ni < 4; ++ni)
          acc[mi][ni] = __builtin_amdgcn_mfma_f32_16x16x32_bf16(a[mi], bb[ni], acc[mi][ni], 0, 0, 0);
    }
  }
  const int b = m0 >> 11;
  float bias[4], vv[4];
#pragma unroll
  for (int ni = 0; ni < 4; ++ni) {
    int u = n0 + wn * 64 + ni * 16 + li;
    bias[ni] = b1[u] + projq[b * UNITS + u];
    vv[ni] = V[u];
  }
#pragma unroll
  for (int mi = 0; mi < 4; ++mi) {
#pragma unroll
    for (int r = 0; r < 4; ++r) {
      float s = 0.f;
#pragma unroll
      for (int ni = 0; ni < 4; ++ni) {
        float x = acc[mi][ni][r] + bias[ni];
        float e = __expf(2.f * x);
        s += (1.f - 2.f / (e + 1.f)) * vv[ni];
      }
      s += __shfl_xor(s, 1);
      s += __shfl_xor(s, 2);
      s += __shfl_xor(s, 4);
      s += __shfl_xor(s, 8);
      if (li == 0) atomicAdd(&scores[m0 + wm * 64 + mi * 16 + hi * 4 + r], s);
    }
  }
}

// ---- softmax over S per batch; bv cancels ----
__global__ void k_softmax(const float* __restrict__ scores, float* __restrict__ wts) {
  __shared__ float red[8];
  int b = blockIdx.x;
  int t = threadIdx.x;
  float v[8];
  float mx = -3.4e38f;
#pragma unroll
  for (int i = 0; i < 8; ++i) {
    v[i] = scores[b * SEQ + i * 256 + t];
    mx = fmaxf(mx, v[i]);
  }
#pragma unroll
  for (int o = 1; o < 64; o <<= 1) mx = fmaxf(mx, __shfl_xor(mx, o));
  if ((t & 63) == 0) red[t >> 6] = mx;
  __syncthreads();
  mx = fmaxf(fmaxf(red[0], red[1]), fmaxf(red[2], red[3]));
  float sum = 0.f;
#pragma unroll
  for (int i = 0; i < 8; ++i) { v[i] = __expf(v[i] - mx); sum += v[i]; }
#pragma unroll
  for (int o = 1; o < 64; o <<= 1) sum += __shfl_xor(sum, o);
  if ((t & 63) == 0) red[4 + (t >> 6)] = sum;
  __syncthreads();
  float inv = 1.f / (red[4] + red[5] + red[6] + red[7]);
#pragma unroll
  for (int i = 0; i < 8; ++i) wts[b * SEQ + i * 256 + t] = v[i] * inv;
}

// ---- context from bf16 values: ctx[b][h] = sum_s w[b][s]*v[b][s][h] ----
__global__ void k_context_bf(const unsigned short* __restrict__ Vb,
                             const float* __restrict__ wts, float* __restrict__ ctx) {
  int b = blockIdx.x, sc = blockIdx.y;
  int h4 = threadIdx.x * 4;
  const unsigned short* vb = Vb + (size_t)b * SEQ * H;
  float a0 = 0, a1 = 0, a2 = 0, a3 = 0;
  int s0 = sc * 128;
#pragma unroll 4
  for (int s = s0; s < s0 + 128; ++s) {
    float w = wts[b * SEQ + s];
    ushort4 v = *reinterpret_cast<const ushort4*>(&vb[(size_t)s * H + h4]);
    a0 = fmaf(w, bf2f(v.x), a0);
    a1 = fmaf(w, bf2f(v.y), a1);
    a2 = fmaf(w, bf2f(v.z), a2);
    a3 = fmaf(w, bf2f(v.w), a3);
  }
  atomicAdd(&ctx[b * H + h4 + 0], a0);
  atomicAdd(&ctx[b * H + h4 + 1], a1);
  atomicAdd(&ctx[b * H + h4 + 2], a2);
  atomicAdd(&ctx[b * H + h4 + 3], a3);
}

// ---- fp32 context (fallback path) ----
__global__ void k_context(const float* __restrict__ values, const float* __restrict__ wts,
                          float* __restrict__ ctx) {
  int b = blockIdx.x, hc = blockIdx.y, sc = blockIdx.z;
  int h = hc * 256 + threadIdx.x;
  const float* vb = values + (size_t)b * SEQ * H;
  float acc = 0.f;
  int s0 = sc * 128;
#pragma unroll 4
  for (int s = s0; s < s0 + 128; ++s)
    acc = fmaf(wts[b * SEQ + s], vb[(size_t)s * H + h], acc);
  atomicAdd(&ctx[b * H + h], acc);
}

extern "C" void kernel_launch(void* const* d_in, const int* in_sizes, int n_in,
                              void* d_out, int out_size, void* d_ws, size_t ws_size,
                              hipStream_t stream) {
  (void)in_sizes; (void)n_in; (void)out_size;
  const float* query  = (const float*)d_in[0];
  const float* values = (const float*)d_in[1];
  const float* W1     = (const float*)d_in[2];
  const float* b1     = (const float*)d_in[3];
  const float* W2     = (const float*)d_in[4];
  const float* b2     = (const float*)d_in[5];
  const float* V      = (const float*)d_in[6];
  // d_in[7] = bv: cancels in softmax -> unused.

  float* out = (float*)d_out;
  float* ctx = out;             // [32][1024]
  float* wts = out + BATCH * H; // [32][2048]

  const size_t vb_bytes = (size_t)M_TOT * H * 2;  // 128 MB
  const size_t need = vb_bytes + (2u << 20) + (256u << 10) + (128u << 10);

  if (ws_size >= need) {
    char* ws = (char*)d_ws;
    unsigned short* Vb  = (unsigned short*)ws;
    unsigned short* W1T = (unsigned short*)(ws + vb_bytes);
    float* scores = (float*)(ws + vb_bytes + (2u << 20));
    float* projq  = (float*)(ws + vb_bytes + (2u << 20) + (256u << 10));

    hipMemsetAsync(scores, 0, M_TOT * sizeof(float), stream);
    hipMemsetAsync(ctx, 0, BATCH * H * sizeof(float), stream);

    k_cast<<<(M_TOT * H / 8) / 256, 256, 0, stream>>>(values, Vb);
    k_transpose_w1<<<dim3(32, 32), dim3(32, 8), 0, stream>>>(W1, W1T);
    k_projq<<<dim3(32, 4), 256, 0, stream>>>(query, W2, b2, projq);
    k_score3<<<(M_TOT / BM) * (UNITS / BN), 512, 0, stream>>>(Vb, W1T, b1, projq, V, scores);
    k_softmax<<<BATCH, 256, 0, stream>>>(scores, wts);
    k_context_bf<<<dim3(BATCH, 16), 256, 0, stream>>>(Vb, wts, ctx);
  } else {
    char* ws = (char*)d_ws;
    unsigned short* W1T = (unsigned short*)ws;
    float* scores = (float*)(ws + (2u << 20));
    float* projq  = (float*)(ws + (2u << 20) + (256u << 10));

    hipMemsetAsync(scores, 0, M_TOT * sizeof(float), stream);
    hipMemsetAsync(ctx, 0, BATCH * H * sizeof(float), stream);

    k_transpose_w1<<<dim3(32, 32), dim3(32, 8), 0, stream>>>(W1, W1T);
    k_projq<<<dim3(32, 4), 256, 0, stream>>>(query, W2, b2, projq);
    k_score_f32<<<dim3(UNITS / FBN, M_TOT / FBM), 256, 0, stream>>>(values, W1T, b1, projq, V, scores);
    k_softmax<<<BATCH, 256, 0, stream>>>(scores, wts);
    k_context<<<dim3(BATCH, H / 256, 16), 256, 0, stream>>>(values, wts, ctx);
  }
}

// Round 7
// 341.085 us; speedup vs baseline: 1.0082x; 1.0082x over previous
//
#include <hip/hip_runtime.h>

#define H 1024
#define UNITS 1024
#define BATCH 32
#define SEQ 2048
#define M_TOT (BATCH * SEQ)  // 65536

typedef __attribute__((ext_vector_type(8))) short bf16x8;
typedef __attribute__((ext_vector_type(8))) unsigned short u16x8;
typedef __attribute__((ext_vector_type(4))) float f32x4;

__device__ __forceinline__ unsigned short f2bf(float f) {
  union { float f; unsigned u; } x; x.f = f;
  unsigned r = x.u + 0x7FFFu + ((x.u >> 16) & 1u);  // RTN-even
  return (unsigned short)(r >> 16);
}
__device__ __forceinline__ float bf2f(unsigned short h) {
  union { unsigned u; float f; } x; x.u = (unsigned)h << 16;
  return x.f;
}

// async global->LDS, 16B per lane; LDS dest = wave-uniform base + lane*16
__device__ __forceinline__ void gll16(const unsigned short* g, unsigned short* l) {
  __builtin_amdgcn_global_load_lds(
      (const __attribute__((address_space(1))) void*)g,
      (__attribute__((address_space(3))) void*)l, 16, 0, 0);
}

// ---- values fp32 -> bf16 (one-shot, BW-bound) ----
__global__ void k_cast(const float* __restrict__ in, unsigned short* __restrict__ out) {
  size_t i = ((size_t)blockIdx.x * 256 + threadIdx.x) * 8;
  float4 v0 = *reinterpret_cast<const float4*>(in + i);
  float4 v1 = *reinterpret_cast<const float4*>(in + i + 4);
  union { unsigned short h[8]; u16x8 v; } p;
  p.h[0] = f2bf(v0.x); p.h[1] = f2bf(v0.y); p.h[2] = f2bf(v0.z); p.h[3] = f2bf(v0.w);
  p.h[4] = f2bf(v1.x); p.h[5] = f2bf(v1.y); p.h[6] = f2bf(v1.z); p.h[7] = f2bf(v1.w);
  *reinterpret_cast<u16x8*>(out + i) = p.v;
}

// ---- W1 [H][U] fp32 -> W1T [U][H] bf16 ----
__global__ void k_transpose_w1(const float* __restrict__ W1, unsigned short* __restrict__ W1T) {
  __shared__ float tile[32][33];
  int bx = blockIdx.x, by = blockIdx.y;
  int tx = threadIdx.x, ty = threadIdx.y;
#pragma unroll
  for (int i = 0; i < 4; ++i)
    tile[ty + i * 8][tx] = W1[(by * 32 + ty + i * 8) * UNITS + bx * 32 + tx];
  __syncthreads();
#pragma unroll
  for (int i = 0; i < 4; ++i)
    W1T[(bx * 32 + ty + i * 8) * H + by * 32 + tx] = f2bf(tile[tx][ty + i * 8]);
}

// ---- projq[b][u] = query[b,:] @ W2[:,u] + b2[u]  (fp32) ----
__global__ void k_projq(const float* __restrict__ query, const float* __restrict__ W2,
                        const float* __restrict__ b2, float* __restrict__ projq) {
  __shared__ float q[H];
  int b = blockIdx.x;
  int u = blockIdx.y * 256 + threadIdx.x;
  for (int i = threadIdx.x; i < H; i += 256) q[i] = query[b * H + i];
  __syncthreads();
  float acc = 0.f;
#pragma unroll 8
  for (int k = 0; k < H; ++k) acc = fmaf(q[k], W2[k * UNITS + u], acc);
  projq[b * UNITS + u] = acc + b2[u];
}

// ============ 256x256 fused GEMM + tanh + dot(V) -> scores ===================
// LDS reshaped to FULL-BK rows: [2 dbuf][256 rows][64 halves] (128-B rows) —
// bank quad = slot only (row*128 wraps all 32 banks). Swizzle is the R3-PROVEN
// involution over 8 slots: physical slot = logical slot ^ (row&7). Store side
// keeps LDS writes linear (gll16 requirement) and pre-swizzles the GLOBAL
// source slot: scol = ((lane&7) ^ (lane>>3))<<3 (rule 21: same involution both
// sides). Read: col = ((kh*4+hi) ^ (li&7))<<3 -> 8 quads x 8 lanes uniform,
// 0 conflicts (measured in R3). R4/R5's 64-B-row layout was +8 cyc/ds_read_b128
// (1.26e7 = 1.57e6 reads x 8) and LDS-serial at MfmaUtil 29%.
// Schedule: per K-tile one vmcnt(0)+barrier (tile-c loads were issued during
// tile c-1's phases 0/1 -> ~1000 cyc cushion), then 4 phases x 16 MFMA with
// next-tile stages issued in phases 0/1. setprio(1) around MFMA clusters.
#define BM 256
#define BN 256
#define NT 16  // K-tiles of 64

__global__ __launch_bounds__(512, 2) void k_score3(
    const unsigned short* __restrict__ Vb,   // values bf16 [M_TOT][H]
    const unsigned short* __restrict__ W1T,  // [UNITS][H] bf16
    const float* __restrict__ b1,
    const float* __restrict__ projq,         // [BATCH][UNITS]
    const float* __restrict__ V,
    float* __restrict__ scores)              // [M_TOT], pre-zeroed
{
  __shared__ unsigned short As[2][256][64];  // 64 KB
  __shared__ unsigned short Bs[2][256][64];  // 64 KB

  const int tid = threadIdx.x;
  const int lane = tid & 63;
  const int wave = tid >> 6;        // 0..7
  const int wm = wave >> 2;         // 0..1 -> rows wm*128..+128
  const int wn = wave & 3;          // 0..3 -> cols wn*64..+64
  const int li = lane & 15, hi = lane >> 4;
  const int lx = li & 7;            // read-swizzle row phase

  // XCD-bijective swizzle: all 4 N-tiles of an M-tile on one XCD, consecutive.
  const int g = blockIdx.x;
  const int xcd = g & 7;
  const int local = g >> 3;          // 0..127
  const int n_t = local & 3;
  const int m_t = xcd + ((local >> 2) << 3);  // 0..255, bijective
  const int m0 = m_t * BM;
  const int n0 = n_t * BN;

  // staging: per wave 4 chunks of 8 rows x 128 B; chunk = 1 gll16 (64x16B)
  const int crow = lane >> 3;                     // row within 8-row chunk
  const int scol = ((lane & 7) ^ crow) << 3;      // pre-swizzled source slot

  auto STAGE_A = [&](int bf, int kt) {
#pragma unroll
    for (int q = 0; q < 4; ++q) {
      int r = wave * 32 + q * 8;
      gll16(&Vb[(size_t)(m0 + r + crow) * H + kt * 64 + scol], &As[bf][r][0]);
    }
  };
  auto STAGE_B = [&](int bf, int kt) {
#pragma unroll
    for (int q = 0; q < 4; ++q) {
      int r = wave * 32 + q * 8;
      gll16(&W1T[(size_t)(n0 + r + crow) * H + kt * 64 + scol], &Bs[bf][r][0]);
    }
  };

  f32x4 acc[8][4] = {};

  // prologue: K-tile 0 -> buf 0 (8 loads)
  STAGE_A(0, 0);
  STAGE_B(0, 0);

#pragma unroll 2
  for (int c = 0; c < NT; ++c) {
    const int buf = c & 1, nbuf = buf ^ 1;
    const int cn = (c < NT - 1) ? c + 1 : NT - 1;  // tail: dummy re-stage

    // tile c ready: own 8 loads (issued during iter c-1, >=2.5 phases ago)
    asm volatile("s_waitcnt vmcnt(0)" ::: "memory");
    __builtin_amdgcn_s_barrier();

    bf16x8 a[8], b0, b1v;

    // ---- phase 0: kh=0, nh=0 ----
    STAGE_A(nbuf, cn);
#pragma unroll
    for (int i = 0; i < 8; ++i)
      a[i] = *reinterpret_cast<const bf16x8*>(
          &As[buf][wm * 128 + i * 16 + li][(hi ^ lx) << 3]);
    b0  = *reinterpret_cast<const bf16x8*>(&Bs[buf][wn * 64 +  0 + li][(hi ^ lx) << 3]);
    b1v = *reinterpret_cast<const bf16x8*>(&Bs[buf][wn * 64 + 16 + li][(hi ^ lx) << 3]);
    __builtin_amdgcn_s_setprio(1);
#pragma unroll
    for (int i = 0; i < 8; ++i) {
      acc[i][0] = __builtin_amdgcn_mfma_f32_16x16x32_bf16(a[i], b0, acc[i][0], 0, 0, 0);
      acc[i][1] = __builtin_amdgcn_mfma_f32_16x16x32_bf16(a[i], b1v, acc[i][1], 0, 0, 0);
    }
    __builtin_amdgcn_s_setprio(0);

    // ---- phase 1: kh=0, nh=1 ----
    STAGE_B(nbuf, cn);
    b0  = *reinterpret_cast<const bf16x8*>(&Bs[buf][wn * 64 + 32 + li][(hi ^ lx) << 3]);
    b1v = *reinterpret_cast<const bf16x8*>(&Bs[buf][wn * 64 + 48 + li][(hi ^ lx) << 3]);
    __builtin_amdgcn_s_setprio(1);
#pragma unroll
    for (int i = 0; i < 8; ++i) {
      acc[i][2] = __builtin_amdgcn_mfma_f32_16x16x32_bf16(a[i], b0, acc[i][2], 0, 0, 0);
      acc[i][3] = __builtin_amdgcn_mfma_f32_16x16x32_bf16(a[i], b1v, acc[i][3], 0, 0, 0);
    }
    __builtin_amdgcn_s_setprio(0);

    // ---- phase 2: kh=1, nh=0 ----
#pragma unroll
    for (int i = 0; i < 8; ++i)
      a[i] = *reinterpret_cast<const bf16x8*>(
          &As[buf][wm * 128 + i * 16 + li][((4 + hi) ^ lx) << 3]);
    b0  = *reinterpret_cast<const bf16x8*>(&Bs[buf][wn * 64 +  0 + li][((4 + hi) ^ lx) << 3]);
    b1v = *reinterpret_cast<const bf16x8*>(&Bs[buf][wn * 64 + 16 + li][((4 + hi) ^ lx) << 3]);
    __builtin_amdgcn_s_setprio(1);
#pragma unroll
    for (int i = 0; i < 8; ++i) {
      acc[i][0] = __builtin_amdgcn_mfma_f32_16x16x32_bf16(a[i], b0, acc[i][0], 0, 0, 0);
      acc[i][1] = __builtin_amdgcn_mfma_f32_16x16x32_bf16(a[i], b1v, acc[i][1], 0, 0, 0);
    }
    __builtin_amdgcn_s_setprio(0);

    // ---- phase 3: kh=1, nh=1 ----
    b0  = *reinterpret_cast<const bf16x8*>(&Bs[buf][wn * 64 + 32 + li][((4 + hi) ^ lx) << 3]);
    b1v = *reinterpret_cast<const bf16x8*>(&Bs[buf][wn * 64 + 48 + li][((4 + hi) ^ lx) << 3]);
    __builtin_amdgcn_s_setprio(1);
#pragma unroll
    for (int i = 0; i < 8; ++i) {
      acc[i][2] = __builtin_amdgcn_mfma_f32_16x16x32_bf16(a[i], b0, acc[i][2], 0, 0, 0);
      acc[i][3] = __builtin_amdgcn_mfma_f32_16x16x32_bf16(a[i], b1v, acc[i][3], 0, 0, 0);
    }
    __builtin_amdgcn_s_setprio(0);
  }

  // epilogue: partial score[row] = sum_u tanh(acc + b1[u] + projq[b][u]) * V[u]
  const int b = m0 >> 11;  // BM=256 divides SEQ=2048 -> batch uniform per block
  float bias[4], vv[4];
#pragma unroll
  for (int j = 0; j < 4; ++j) {
    int u = n0 + wn * 64 + j * 16 + li;
    bias[j] = b1[u] + projq[b * UNITS + u];
    vv[j] = V[u];
  }
#pragma unroll
  for (int mi = 0; mi < 8; ++mi) {
#pragma unroll
    for (int r = 0; r < 4; ++r) {
      float s = 0.f;
#pragma unroll
      for (int j = 0; j < 4; ++j) {
        float x = acc[mi][j][r] + bias[j];
        float e = __expf(2.f * x);       // tanh(x) = 1 - 2/(e^(2x)+1)
        s += (1.f - 2.f / (e + 1.f)) * vv[j];
      }
      s += __shfl_xor(s, 1);
      s += __shfl_xor(s, 2);
      s += __shfl_xor(s, 4);
      s += __shfl_xor(s, 8);
      if (li == 0) {
        int row = m0 + wm * 128 + mi * 16 + hi * 4 + r;
        atomicAdd(&scores[row], s);
      }
    }
  }
}

// ---- fallback fp32-A score kernel (used only if ws too small) ----
#define FBM 128
#define FBN 128
#define FBK 64
#define LDK 72
__global__ __launch_bounds__(256) void k_score_f32(
    const float* __restrict__ values, const unsigned short* __restrict__ W1T,
    const float* __restrict__ b1, const float* __restrict__ projq,
    const float* __restrict__ V, float* __restrict__ scores)
{
  __shared__ unsigned short Asf[FBM][LDK];
  __shared__ unsigned short Bsf[FBN][LDK];
  const int tid = threadIdx.x;
  const int lane = tid & 63;
  const int wave = tid >> 6;
  const int wm = wave >> 1, wn = wave & 1;
  const int li = lane & 15, hi = lane >> 4;
  const int n0 = blockIdx.x * FBN;
  const int m0 = blockIdx.y * FBM;
  f32x4 acc[4][4] = {};
  for (int k0 = 0; k0 < H; k0 += FBK) {
    __syncthreads();
#pragma unroll
    for (int q = 0; q < 8; ++q) {
      int idx = q * 256 + tid;
      int row = idx >> 4;
      int kc = (idx & 15) << 2;
      float4 v = *reinterpret_cast<const float4*>(&values[(size_t)(m0 + row) * H + k0 + kc]);
      union { unsigned short h[4]; unsigned long long u64; } p;
      p.h[0] = f2bf(v.x); p.h[1] = f2bf(v.y); p.h[2] = f2bf(v.z); p.h[3] = f2bf(v.w);
      *reinterpret_cast<unsigned long long*>(&Asf[row][kc]) = p.u64;
    }
#pragma unroll
    for (int q = 0; q < 4; ++q) {
      int idx = q * 256 + tid;
      int row = idx >> 3;
      int kc = (idx & 7) << 3;
      *reinterpret_cast<u16x8*>(&Bsf[row][kc]) =
          *reinterpret_cast<const u16x8*>(&W1T[(size_t)(n0 + row) * H + k0 + kc]);
    }
    __syncthreads();
#pragma unroll
    for (int ks = 0; ks < 2; ++ks) {
      const int kofs = ks * 32 + 8 * hi;
      bf16x8 a[4], bb[4];
#pragma unroll
      for (int i = 0; i < 4; ++i)
        a[i] = *reinterpret_cast<const bf16x8*>(&Asf[wm * 64 + i * 16 + li][kofs]);
#pragma unroll
      for (int i = 0; i < 4; ++i)
        bb[i] = *reinterpret_cast<const bf16x8*>(&Bsf[wn * 64 + i * 16 + li][kofs]);
#pragma unroll
      for (int mi = 0; mi < 4; ++mi)
#pragma unroll
        for (int ni = 0; ni < 4; ++ni)
          acc[mi][ni] = __builtin_amdgcn_mfma_f32_16x16x32_bf16(a[mi], bb[ni], acc[mi][ni], 0, 0, 0);
    }
  }
  const int b = m0 >> 11;
  float bias[4], vv[4];
#pragma unroll
  for (int ni = 0; ni < 4; ++ni) {
    int u = n0 + wn * 64 + ni * 16 + li;
    bias[ni] = b1[u] + projq[b * UNITS + u];
    vv[ni] = V[u];
  }
#pragma unroll
  for (int mi = 0; mi < 4; ++mi) {
#pragma unroll
    for (int r = 0; r < 4; ++r) {
      float s = 0.f;
#pragma unroll
      for (int ni = 0; ni < 4; ++ni) {
        float x = acc[mi][ni][r] + bias[ni];
        float e = __expf(2.f * x);
        s += (1.f - 2.f / (e + 1.f)) * vv[ni];
      }
      s += __shfl_xor(s, 1);
      s += __shfl_xor(s, 2);
      s += __shfl_xor(s, 4);
      s += __shfl_xor(s, 8);
      if (li == 0) atomicAdd(&scores[m0 + wm * 64 + mi * 16 + hi * 4 + r], s);
    }
  }
}

// ---- softmax over S per batch; bv cancels ----
__global__ void k_softmax(const float* __restrict__ scores, float* __restrict__ wts) {
  __shared__ float red[8];
  int b = blockIdx.x;
  int t = threadIdx.x;
  float v[8];
  float mx = -3.4e38f;
#pragma unroll
  for (int i = 0; i < 8; ++i) {
    v[i] = scores[b * SEQ + i * 256 + t];
    mx = fmaxf(mx, v[i]);
  }
#pragma unroll
  for (int o = 1; o < 64; o <<= 1) mx = fmaxf(mx, __shfl_xor(mx, o));
  if ((t & 63) == 0) red[t >> 6] = mx;
  __syncthreads();
  mx = fmaxf(fmaxf(red[0], red[1]), fmaxf(red[2], red[3]));
  float sum = 0.f;
#pragma unroll
  for (int i = 0; i < 8; ++i) { v[i] = __expf(v[i] - mx); sum += v[i]; }
#pragma unroll
  for (int o = 1; o < 64; o <<= 1) sum += __shfl_xor(sum, o);
  if ((t & 63) == 0) red[4 + (t >> 6)] = sum;
  __syncthreads();
  float inv = 1.f / (red[4] + red[5] + red[6] + red[7]);
#pragma unroll
  for (int i = 0; i < 8; ++i) wts[b * SEQ + i * 256 + t] = v[i] * inv;
}

// ---- context from bf16 values: ctx[b][h] = sum_s w[b][s]*v[b][s][h] ----
__global__ void k_context_bf(const unsigned short* __restrict__ Vb,
                             const float* __restrict__ wts, float* __restrict__ ctx) {
  int b = blockIdx.x, sc = blockIdx.y;
  int h4 = threadIdx.x * 4;
  const unsigned short* vb = Vb + (size_t)b * SEQ * H;
  float a0 = 0, a1 = 0, a2 = 0, a3 = 0;
  int s0 = sc * 128;
#pragma unroll 4
  for (int s = s0; s < s0 + 128; ++s) {
    float w = wts[b * SEQ + s];
    ushort4 v = *reinterpret_cast<const ushort4*>(&vb[(size_t)s * H + h4]);
    a0 = fmaf(w, bf2f(v.x), a0);
    a1 = fmaf(w, bf2f(v.y), a1);
    a2 = fmaf(w, bf2f(v.z), a2);
    a3 = fmaf(w, bf2f(v.w), a3);
  }
  atomicAdd(&ctx[b * H + h4 + 0], a0);
  atomicAdd(&ctx[b * H + h4 + 1], a1);
  atomicAdd(&ctx[b * H + h4 + 2], a2);
  atomicAdd(&ctx[b * H + h4 + 3], a3);
}

// ---- fp32 context (fallback path) ----
__global__ void k_context(const float* __restrict__ values, const float* __restrict__ wts,
                          float* __restrict__ ctx) {
  int b = blockIdx.x, hc = blockIdx.y, sc = blockIdx.z;
  int h = hc * 256 + threadIdx.x;
  const float* vb = values + (size_t)b * SEQ * H;
  float acc = 0.f;
  int s0 = sc * 128;
#pragma unroll 4
  for (int s = s0; s < s0 + 128; ++s)
    acc = fmaf(wts[b * SEQ + s], vb[(size_t)s * H + h], acc);
  atomicAdd(&ctx[b * H + h], acc);
}

extern "C" void kernel_launch(void* const* d_in, const int* in_sizes, int n_in,
                              void* d_out, int out_size, void* d_ws, size_t ws_size,
                              hipStream_t stream) {
  (void)in_sizes; (void)n_in; (void)out_size;
  const float* query  = (const float*)d_in[0];
  const float* values = (const float*)d_in[1];
  const float* W1     = (const float*)d_in[2];
  const float* b1     = (const float*)d_in[3];
  const float* W2     = (const float*)d_in[4];
  const float* b2     = (const float*)d_in[5];
  const float* V      = (const float*)d_in[6];
  // d_in[7] = bv: cancels in softmax -> unused.

  float* out = (float*)d_out;
  float* ctx = out;             // [32][1024]
  float* wts = out + BATCH * H; // [32][2048]

  const size_t vb_bytes = (size_t)M_TOT * H * 2;  // 128 MB
  const size_t need = vb_bytes + (2u << 20) + (256u << 10) + (128u << 10);

  if (ws_size >= need) {
    char* ws = (char*)d_ws;
    unsigned short* Vb  = (unsigned short*)ws;
    unsigned short* W1T = (unsigned short*)(ws + vb_bytes);
    float* scores = (float*)(ws + vb_bytes + (2u << 20));
    float* projq  = (float*)(ws + vb_bytes + (2u << 20) + (256u << 10));

    hipMemsetAsync(scores, 0, M_TOT * sizeof(float), stream);
    hipMemsetAsync(ctx, 0, BATCH * H * sizeof(float), stream);

    k_cast<<<(M_TOT * H / 8) / 256, 256, 0, stream>>>(values, Vb);
    k_transpose_w1<<<dim3(32, 32), dim3(32, 8), 0, stream>>>(W1, W1T);
    k_projq<<<dim3(32, 4), 256, 0, stream>>>(query, W2, b2, projq);
    k_score3<<<(M_TOT / BM) * (UNITS / BN), 512, 0, stream>>>(Vb, W1T, b1, projq, V, scores);
    k_softmax<<<BATCH, 256, 0, stream>>>(scores, wts);
    k_context_bf<<<dim3(BATCH, 16), 256, 0, stream>>>(Vb, wts, ctx);
  } else {
    char* ws = (char*)d_ws;
    unsigned short* W1T = (unsigned short*)ws;
    float* scores = (float*)(ws + (2u << 20));
    float* projq  = (float*)(ws + (2u << 20) + (256u << 10));

    hipMemsetAsync(scores, 0, M_TOT * sizeof(float), stream);
    hipMemsetAsync(ctx, 0, BATCH * H * sizeof(float), stream);

    k_transpose_w1<<<dim3(32, 32), dim3(32, 8), 0, stream>>>(W1, W1T);
    k_projq<<<dim3(32, 4), 256, 0, stream>>>(query, W2, b2, projq);
    k_score_f32<<<dim3(UNITS / FBN, M_TOT / FBM), 256, 0, stream>>>(values, W1T, b1, projq, V, scores);
    k_softmax<<<BATCH, 256, 0, stream>>>(scores, wts);
    k_context<<<dim3(BATCH, H / 256, 16), 256, 0, stream>>>(values, wts, ctx);
  }
}

// Round 8
// 328.227 us; speedup vs baseline: 1.0477x; 1.0392x over previous
//
#include <hip/hip_runtime.h>

#define H 1024
#define UNITS 1024
#define BATCH 32
#define SEQ 2048
#define M_TOT (BATCH * SEQ)  // 65536

typedef __attribute__((ext_vector_type(8))) short bf16x8;
typedef __attribute__((ext_vector_type(8))) unsigned short u16x8;
typedef __attribute__((ext_vector_type(4))) float f32x4;

__device__ __forceinline__ unsigned short f2bf(float f) {
  union { float f; unsigned u; } x; x.f = f;
  unsigned r = x.u + 0x7FFFu + ((x.u >> 16) & 1u);  // RTN-even
  return (unsigned short)(r >> 16);
}
__device__ __forceinline__ float bf2f(unsigned short h) {
  union { unsigned u; float f; } x; x.u = (unsigned)h << 16;
  return x.f;
}

// async global->LDS, 16B per lane; LDS dest = wave-uniform base + lane*16
__device__ __forceinline__ void gll16(const unsigned short* g, unsigned short* l) {
  __builtin_amdgcn_global_load_lds(
      (const __attribute__((address_space(1))) void*)g,
      (__attribute__((address_space(3))) void*)l, 16, 0, 0);
}

// ---- values fp32 -> bf16 (one-shot, BW-bound) ----
__global__ void k_cast(const float* __restrict__ in, unsigned short* __restrict__ out) {
  size_t i = ((size_t)blockIdx.x * 256 + threadIdx.x) * 8;
  float4 v0 = *reinterpret_cast<const float4*>(in + i);
  float4 v1 = *reinterpret_cast<const float4*>(in + i + 4);
  union { unsigned short h[8]; u16x8 v; } p;
  p.h[0] = f2bf(v0.x); p.h[1] = f2bf(v0.y); p.h[2] = f2bf(v0.z); p.h[3] = f2bf(v0.w);
  p.h[4] = f2bf(v1.x); p.h[5] = f2bf(v1.y); p.h[6] = f2bf(v1.z); p.h[7] = f2bf(v1.w);
  *reinterpret_cast<u16x8*>(out + i) = p.v;
}

// ---- W1 [H][U] fp32 -> W1T [U][H] bf16 ----
__global__ void k_transpose_w1(const float* __restrict__ W1, unsigned short* __restrict__ W1T) {
  __shared__ float tile[32][33];
  int bx = blockIdx.x, by = blockIdx.y;
  int tx = threadIdx.x, ty = threadIdx.y;
#pragma unroll
  for (int i = 0; i < 4; ++i)
    tile[ty + i * 8][tx] = W1[(by * 32 + ty + i * 8) * UNITS + bx * 32 + tx];
  __syncthreads();
#pragma unroll
  for (int i = 0; i < 4; ++i)
    W1T[(bx * 32 + ty + i * 8) * H + by * 32 + tx] = f2bf(tile[tx][ty + i * 8]);
}

// ---- projq[b][u] = query[b,:] @ W2[:,u] + b2[u]  (fp32) ----
__global__ void k_projq(const float* __restrict__ query, const float* __restrict__ W2,
                        const float* __restrict__ b2, float* __restrict__ projq) {
  __shared__ float q[H];
  int b = blockIdx.x;
  int u = blockIdx.y * 256 + threadIdx.x;
  for (int i = threadIdx.x; i < H; i += 256) q[i] = query[b * H + i];
  __syncthreads();
  float acc = 0.f;
#pragma unroll 8
  for (int k = 0; k < H; ++k) acc = fmaf(q[k], W2[k * UNITS + u], acc);
  projq[b * UNITS + u] = acc + b2[u];
}

// ============ 256x256 fused GEMM + tanh + dot(V) -> scores ===================
// T4 counted-vmcnt, depth-3 prefetch: BK=32, RING-4 LDS buffers (128 KB).
// Per wave per tile: 4 gll16 (2 A + 2 B), 12 ds_read_b128, 32 MFMA.
// Steady state 12 loads outstanding/wave; at tile top s_waitcnt vmcnt(8)
// waits ONLY tile-c's 4 loads (issued 3 tiles earlier); tiles c+1,c+2 stay in
// flight ACROSS the barrier — never drained to 0 (T4; R6's vmcnt(0)-per-tile
// was the m218 drain0 cliff: MfmaUtil stuck at 29%).
// Layout keeps the R6-PROVEN conflict-free geometry by packing 2 logical rows
// per 128-B LDS row: tile [256 m][32 k] -> lds [128][64]; logical slot
// s = (m&1)*4 + (k>>3); physical slot p = s ^ (ldsrow&7).
//   store (linear LDS, pre-swizzled GLOBAL source): lane l of a 16-row chunk:
//     s=(l&7)^(l>>3), m=2*(l>>3)+(s>>2), khalf=(s&3)*8
//   read (frag row i*16+li, k-slice hi*8): p=((li&1)*4+hi)^(li>>1)
// Bank census: 8 lanes per 16-B quad = the wave64 b128 floor (conflict-free).
// Ring distance 3 + one barrier/tile => buffer reuse race-free.
#define BM 256
#define BN 256
#define NKT 32  // K-tiles of 32

__global__ __launch_bounds__(512, 2) void k_score3(
    const unsigned short* __restrict__ Vb,   // values bf16 [M_TOT][H]
    const unsigned short* __restrict__ W1T,  // [UNITS][H] bf16
    const float* __restrict__ b1,
    const float* __restrict__ projq,         // [BATCH][UNITS]
    const float* __restrict__ V,
    float* __restrict__ scores)              // [M_TOT], pre-zeroed
{
  __shared__ unsigned short As[4][128][64];  // 64 KB (ring of 4 K-tiles)
  __shared__ unsigned short Bs[4][128][64];  // 64 KB

  const int tid = threadIdx.x;
  const int lane = tid & 63;
  const int wave = tid >> 6;        // 0..7
  const int wm = wave >> 2;         // 0..1 -> rows wm*128..+128
  const int wn = wave & 3;          // 0..3 -> cols wn*64..+64
  const int li = lane & 15, hi = lane >> 4;
  const int lr2 = li >> 1;
  const int pcol = (((((li & 1) << 2) + hi) ^ lr2) & 7) << 3;  // read slot (halves)

  // XCD-bijective swizzle: all 4 N-tiles of an M-tile on one XCD, consecutive.
  const int g = blockIdx.x;
  const int xcd = g & 7;
  const int local = g >> 3;          // 0..127
  const int n_t = local & 3;
  const int m_t = xcd + ((local >> 2) << 3);  // 0..255, bijective
  const int m0 = m_t * BM;
  const int n0 = n_t * BN;

  // staging: chunk = 16 global rows x 32 halves = 1 KB = one gll16.
  // lane l: s=(l&7)^(l>>3); grow = 2*(l>>3)+(s>>2); gcol halves = (s&3)*8
  const int sL = (lane & 7) ^ (lane >> 3);
  const int srow = 2 * (lane >> 3) + (sL >> 2);
  const int scol = (sL & 3) << 3;

  auto STAGE_A = [&](int bf, int kt) {
#pragma unroll
    for (int q = 0; q < 2; ++q) {
      int mb = wave * 32 + q * 16;
      gll16(&Vb[(size_t)(m0 + mb + srow) * H + kt * 32 + scol],
            &As[bf][wave * 16 + q * 8][0]);
    }
  };
  auto STAGE_B = [&](int bf, int kt) {
#pragma unroll
    for (int q = 0; q < 2; ++q) {
      int mb = wave * 32 + q * 16;
      gll16(&W1T[(size_t)(n0 + mb + srow) * H + kt * 32 + scol],
            &Bs[bf][wave * 16 + q * 8][0]);
    }
  };

  f32x4 acc[8][4] = {};

  // prologue: stage tiles 0,1,2 (12 loads/wave; issue order = ledger order)
  STAGE_A(0, 0); STAGE_B(0, 0);
  STAGE_A(1, 1); STAGE_B(1, 1);
  STAGE_A(2, 2); STAGE_B(2, 2);

#pragma unroll 4
  for (int c = 0; c < NKT; ++c) {
    const int buf = c & 3;
    const int nbuf = (c + 3) & 3;
    const int cn = (c < NKT - 3) ? c + 3 : NKT - 1;  // tail: dup-stage tile 31

    // tile c's 4 loads landed (issued 3 tiles ago); c+1,c+2 stay in flight
    asm volatile("s_waitcnt vmcnt(8)" ::: "memory");
    __builtin_amdgcn_s_barrier();

    bf16x8 a[8], b[4];
#pragma unroll
    for (int i = 0; i < 8; ++i)
      a[i] = *reinterpret_cast<const bf16x8*>(&As[buf][wm * 64 + i * 8 + lr2][pcol]);
    STAGE_A(nbuf, cn);
#pragma unroll
    for (int j = 0; j < 4; ++j)
      b[j] = *reinterpret_cast<const bf16x8*>(&Bs[buf][wn * 32 + j * 8 + lr2][pcol]);
    STAGE_B(nbuf, cn);

    __builtin_amdgcn_s_setprio(1);
#pragma unroll
    for (int i = 0; i < 8; ++i)
#pragma unroll
      for (int j = 0; j < 4; ++j)
        acc[i][j] = __builtin_amdgcn_mfma_f32_16x16x32_bf16(a[i], b[j], acc[i][j], 0, 0, 0);
    __builtin_amdgcn_s_setprio(0);
  }

  // epilogue: partial score[row] = sum_u tanh(acc + b1[u] + projq[b][u]) * V[u]
  const int b = m0 >> 11;  // BM=256 divides SEQ=2048 -> batch uniform per block
  float bias[4], vv[4];
#pragma unroll
  for (int j = 0; j < 4; ++j) {
    int u = n0 + wn * 64 + j * 16 + li;
    bias[j] = b1[u] + projq[b * UNITS + u];
    vv[j] = V[u];
  }
#pragma unroll
  for (int mi = 0; mi < 8; ++mi) {
#pragma unroll
    for (int r = 0; r < 4; ++r) {
      float s = 0.f;
#pragma unroll
      for (int j = 0; j < 4; ++j) {
        float x = acc[mi][j][r] + bias[j];
        float e = __expf(2.f * x);       // tanh(x) = 1 - 2/(e^(2x)+1)
        s += (1.f - 2.f / (e + 1.f)) * vv[j];
      }
      s += __shfl_xor(s, 1);
      s += __shfl_xor(s, 2);
      s += __shfl_xor(s, 4);
      s += __shfl_xor(s, 8);
      if (li == 0) {
        int row = m0 + wm * 128 + mi * 16 + hi * 4 + r;
        atomicAdd(&scores[row], s);
      }
    }
  }
}

// ---- fallback fp32-A score kernel (used only if ws too small) ----
#define FBM 128
#define FBN 128
#define FBK 64
#define LDK 72
__global__ __launch_bounds__(256) void k_score_f32(
    const float* __restrict__ values, const unsigned short* __restrict__ W1T,
    const float* __restrict__ b1, const float* __restrict__ projq,
    const float* __restrict__ V, float* __restrict__ scores)
{
  __shared__ unsigned short Asf[FBM][LDK];
  __shared__ unsigned short Bsf[FBN][LDK];
  const int tid = threadIdx.x;
  const int lane = tid & 63;
  const int wave = tid >> 6;
  const int wm = wave >> 1, wn = wave & 1;
  const int li = lane & 15, hi = lane >> 4;
  const int n0 = blockIdx.x * FBN;
  const int m0 = blockIdx.y * FBM;
  f32x4 acc[4][4] = {};
  for (int k0 = 0; k0 < H; k0 += FBK) {
    __syncthreads();
#pragma unroll
    for (int q = 0; q < 8; ++q) {
      int idx = q * 256 + tid;
      int row = idx >> 4;
      int kc = (idx & 15) << 2;
      float4 v = *reinterpret_cast<const float4*>(&values[(size_t)(m0 + row) * H + k0 + kc]);
      union { unsigned short h[4]; unsigned long long u64; } p;
      p.h[0] = f2bf(v.x); p.h[1] = f2bf(v.y); p.h[2] = f2bf(v.z); p.h[3] = f2bf(v.w);
      *reinterpret_cast<unsigned long long*>(&Asf[row][kc]) = p.u64;
    }
#pragma unroll
    for (int q = 0; q < 4; ++q) {
      int idx = q * 256 + tid;
      int row = idx >> 3;
      int kc = (idx & 7) << 3;
      *reinterpret_cast<u16x8*>(&Bsf[row][kc]) =
          *reinterpret_cast<const u16x8*>(&W1T[(size_t)(n0 + row) * H + k0 + kc]);
    }
    __syncthreads();
#pragma unroll
    for (int ks = 0; ks < 2; ++ks) {
      const int kofs = ks * 32 + 8 * hi;
      bf16x8 a[4], bb[4];
#pragma unroll
      for (int i = 0; i < 4; ++i)
        a[i] = *reinterpret_cast<const bf16x8*>(&Asf[wm * 64 + i * 16 + li][kofs]);
#pragma unroll
      for (int i = 0; i < 4; ++i)
        bb[i] = *reinterpret_cast<const bf16x8*>(&Bsf[wn * 64 + i * 16 + li][kofs]);
#pragma unroll
      for (int mi = 0; mi < 4; ++mi)
#pragma unroll
        for (int ni = 0; ni < 4; ++ni)
          acc[mi][ni] = __builtin_amdgcn_mfma_f32_16x16x32_bf16(a[mi], bb[ni], acc[mi][ni], 0, 0, 0);
    }
  }
  const int b = m0 >> 11;
  float bias[4], vv[4];
#pragma unroll
  for (int ni = 0; ni < 4; ++ni) {
    int u = n0 + wn * 64 + ni * 16 + li;
    bias[ni] = b1[u] + projq[b * UNITS + u];
    vv[ni] = V[u];
  }
#pragma unroll
  for (int mi = 0; mi < 4; ++mi) {
#pragma unroll
    for (int r = 0; r < 4; ++r) {
      float s = 0.f;
#pragma unroll
      for (int ni = 0; ni < 4; ++ni) {
        float x = acc[mi][ni][r] + bias[ni];
        float e = __expf(2.f * x);
        s += (1.f - 2.f / (e + 1.f)) * vv[ni];
      }
      s += __shfl_xor(s, 1);
      s += __shfl_xor(s, 2);
      s += __shfl_xor(s, 4);
      s += __shfl_xor(s, 8);
      if (li == 0) atomicAdd(&scores[m0 + wm * 64 + mi * 16 + hi * 4 + r], s);
    }
  }
}

// ---- softmax over S per batch; bv cancels ----
__global__ void k_softmax(const float* __restrict__ scores, float* __restrict__ wts) {
  __shared__ float red[8];
  int b = blockIdx.x;
  int t = threadIdx.x;
  float v[8];
  float mx = -3.4e38f;
#pragma unroll
  for (int i = 0; i < 8; ++i) {
    v[i] = scores[b * SEQ + i * 256 + t];
    mx = fmaxf(mx, v[i]);
  }
#pragma unroll
  for (int o = 1; o < 64; o <<= 1) mx = fmaxf(mx, __shfl_xor(mx, o));
  if ((t & 63) == 0) red[t >> 6] = mx;
  __syncthreads();
  mx = fmaxf(fmaxf(red[0], red[1]), fmaxf(red[2], red[3]));
  float sum = 0.f;
#pragma unroll
  for (int i = 0; i < 8; ++i) { v[i] = __expf(v[i] - mx); sum += v[i]; }
#pragma unroll
  for (int o = 1; o < 64; o <<= 1) sum += __shfl_xor(sum, o);
  if ((t & 63) == 0) red[4 + (t >> 6)] = sum;
  __syncthreads();
  float inv = 1.f / (red[4] + red[5] + red[6] + red[7]);
#pragma unroll
  for (int i = 0; i < 8; ++i) wts[b * SEQ + i * 256 + t] = v[i] * inv;
}

// ---- context from bf16 values: ctx[b][h] = sum_s w[b][s]*v[b][s][h] ----
__global__ void k_context_bf(const unsigned short* __restrict__ Vb,
                             const float* __restrict__ wts, float* __restrict__ ctx) {
  int b = blockIdx.x, sc = blockIdx.y;
  int h4 = threadIdx.x * 4;
  const unsigned short* vb = Vb + (size_t)b * SEQ * H;
  float a0 = 0, a1 = 0, a2 = 0, a3 = 0;
  int s0 = sc * 128;
#pragma unroll 4
  for (int s = s0; s < s0 + 128; ++s) {
    float w = wts[b * SEQ + s];
    ushort4 v = *reinterpret_cast<const ushort4*>(&vb[(size_t)s * H + h4]);
    a0 = fmaf(w, bf2f(v.x), a0);
    a1 = fmaf(w, bf2f(v.y), a1);
    a2 = fmaf(w, bf2f(v.z), a2);
    a3 = fmaf(w, bf2f(v.w), a3);
  }
  atomicAdd(&ctx[b * H + h4 + 0], a0);
  atomicAdd(&ctx[b * H + h4 + 1], a1);
  atomicAdd(&ctx[b * H + h4 + 2], a2);
  atomicAdd(&ctx[b * H + h4 + 3], a3);
}

// ---- fp32 context (fallback path) ----
__global__ void k_context(const float* __restrict__ values, const float* __restrict__ wts,
                          float* __restrict__ ctx) {
  int b = blockIdx.x, hc = blockIdx.y, sc = blockIdx.z;
  int h = hc * 256 + threadIdx.x;
  const float* vb = values + (size_t)b * SEQ * H;
  float acc = 0.f;
  int s0 = sc * 128;
#pragma unroll 4
  for (int s = s0; s < s0 + 128; ++s)
    acc = fmaf(wts[b * SEQ + s], vb[(size_t)s * H + h], acc);
  atomicAdd(&ctx[b * H + h], acc);
}

extern "C" void kernel_launch(void* const* d_in, const int* in_sizes, int n_in,
                              void* d_out, int out_size, void* d_ws, size_t ws_size,
                              hipStream_t stream) {
  (void)in_sizes; (void)n_in; (void)out_size;
  const float* query  = (const float*)d_in[0];
  const float* values = (const float*)d_in[1];
  const float* W1     = (const float*)d_in[2];
  const float* b1     = (const float*)d_in[3];
  const float* W2     = (const float*)d_in[4];
  const float* b2     = (const float*)d_in[5];
  const float* V      = (const float*)d_in[6];
  // d_in[7] = bv: cancels in softmax -> unused.

  float* out = (float*)d_out;
  float* ctx = out;             // [32][1024]
  float* wts = out + BATCH * H; // [32][2048]

  const size_t vb_bytes = (size_t)M_TOT * H * 2;  // 128 MB
  const size_t need = vb_bytes + (2u << 20) + (256u << 10) + (128u << 10);

  if (ws_size >= need) {
    char* ws = (char*)d_ws;
    unsigned short* Vb  = (unsigned short*)ws;
    unsigned short* W1T = (unsigned short*)(ws + vb_bytes);
    float* scores = (float*)(ws + vb_bytes + (2u << 20));
    float* projq  = (float*)(ws + vb_bytes + (2u << 20) + (256u << 10));

    hipMemsetAsync(scores, 0, M_TOT * sizeof(float), stream);
    hipMemsetAsync(ctx, 0, BATCH * H * sizeof(float), stream);

    k_cast<<<(M_TOT * H / 8) / 256, 256, 0, stream>>>(values, Vb);
    k_transpose_w1<<<dim3(32, 32), dim3(32, 8), 0, stream>>>(W1, W1T);
    k_projq<<<dim3(32, 4), 256, 0, stream>>>(query, W2, b2, projq);
    k_score3<<<(M_TOT / BM) * (UNITS / BN), 512, 0, stream>>>(Vb, W1T, b1, projq, V, scores);
    k_softmax<<<BATCH, 256, 0, stream>>>(scores, wts);
    k_context_bf<<<dim3(BATCH, 16), 256, 0, stream>>>(Vb, wts, ctx);
  } else {
    char* ws = (char*)d_ws;
    unsigned short* W1T = (unsigned short*)ws;
    float* scores = (float*)(ws + (2u << 20));
    float* projq  = (float*)(ws + (2u << 20) + (256u << 10));

    hipMemsetAsync(scores, 0, M_TOT * sizeof(float), stream);
    hipMemsetAsync(ctx, 0, BATCH * H * sizeof(float), stream);

    k_transpose_w1<<<dim3(32, 32), dim3(32, 8), 0, stream>>>(W1, W1T);
    k_projq<<<dim3(32, 4), 256, 0, stream>>>(query, W2, b2, projq);
    k_score_f32<<<dim3(UNITS / FBN, M_TOT / FBM), 256, 0, stream>>>(values, W1T, b1, projq, V, scores);
    k_softmax<<<BATCH, 256, 0, stream>>>(scores, wts);
    k_context<<<dim3(BATCH, H / 256, 16), 256, 0, stream>>>(values, wts, ctx);
  }
}